// Round 1
// baseline (185.655 us; speedup 1.0000x reference)
//
#include <hip/hip_runtime.h>

// ANOVA kernel order 3:  out[b] = sum_e e3(x[b, :, e])
// x: (8192, 64, 64) fp32, row-major, e innermost.
//
// R5: same mapping as R4 (one wave per batch row; load i covers float4 units
// [i*64,(i+1)*64) -> 1 KB contiguous per wave-load; lane owns fields
// {4i + (lane>>4)} for embedding group g = lane&15; ESP merge over h then
// component/g reduce). Change vs R4: occupancy push.
//   - __launch_bounds__(256, 8): force <=64 VGPR -> 8 waves/SIMD (32/CU),
//     up from ~5 waves/SIMD when unroll-16 hoisted ~16 float4 loads.
//   - Hand-pipelined 2x4 double buffer (max 8 live float4 = 32 VGPR of data)
//     so the 64-VGPR cap doesn't induce spills; 4-8 loads stay in flight per
//     wave while TLP doubles.
// Theory: kernel is HBM-latency-bound at 5.42 TB/s (86% of 6.3 copy ceiling;
// fills in the same trace sustain 6.9 TB/s one-directional). More resident
// waves -> fuller per-CU request queue -> ~6.3+ TB/s, kernel ~21 us.

constexpr int BATCH = 8192;

__device__ inline float4 shfl_xor4(float4 v, int d) {
    float4 r;
    r.x = __shfl_xor(v.x, d);
    r.y = __shfl_xor(v.y, d);
    r.z = __shfl_xor(v.z, d);
    r.w = __shfl_xor(v.w, d);
    return r;
}

// ESP DP step; order matters: s3 uses old s2, s2 uses old s1.
#define ESP_STEP(v)                                                            \
    s3.x = fmaf(s2.x, (v).x, s3.x); s2.x = fmaf(s1.x, (v).x, s2.x); s1.x += (v).x; \
    s3.y = fmaf(s2.y, (v).y, s3.y); s2.y = fmaf(s1.y, (v).y, s2.y); s1.y += (v).y; \
    s3.z = fmaf(s2.z, (v).z, s3.z); s2.z = fmaf(s1.z, (v).z, s2.z); s1.z += (v).z; \
    s3.w = fmaf(s2.w, (v).w, s3.w); s2.w = fmaf(s1.w, (v).w, s2.w); s1.w += (v).w;

__global__ __launch_bounds__(256, 8) void anova3_kernel(const float* __restrict__ x,
                                                        float* __restrict__ out) {
    const int tid  = blockIdx.x * 256 + threadIdx.x;
    const int lane = threadIdx.x & 63;
    const int b    = tid >> 6;        // one wave per batch row

    // Row = 1024 float4 units. Load i covers units [i*64, (i+1)*64): 1 KB contiguous.
    const float4* xp = reinterpret_cast<const float4*>(x)
                     + (size_t)b * 1024 + lane;

    float4 s1 = make_float4(0.f, 0.f, 0.f, 0.f);
    float4 s2 = s1, s3 = s1;

    // Two 4-load batches in flight; process i = 0..15 in order (identical
    // FP order to R4).
    float4 a0 = xp[0 * 64], a1 = xp[1 * 64], a2 = xp[2 * 64], a3 = xp[3 * 64];
    float4 b0 = xp[4 * 64], b1 = xp[5 * 64], b2 = xp[6 * 64], b3 = xp[7 * 64];

    ESP_STEP(a0) ESP_STEP(a1) ESP_STEP(a2) ESP_STEP(a3)      // i = 0..3
    a0 = xp[8 * 64]; a1 = xp[9 * 64]; a2 = xp[10 * 64]; a3 = xp[11 * 64];

    ESP_STEP(b0) ESP_STEP(b1) ESP_STEP(b2) ESP_STEP(b3)      // i = 4..7
    b0 = xp[12 * 64]; b1 = xp[13 * 64]; b2 = xp[14 * 64]; b3 = xp[15 * 64];

    ESP_STEP(a0) ESP_STEP(a1) ESP_STEP(a2) ESP_STEP(a3)      // i = 8..11
    ESP_STEP(b0) ESP_STEP(b1) ESP_STEP(b2) ESP_STEP(b3)      // i = 12..15

    // Merge the 4 disjoint field subsets across h = lane>>4.
#pragma unroll
    for (int d = 16; d <= 32; d <<= 1) {
        float4 o1 = shfl_xor4(s1, d);
        float4 o2 = shfl_xor4(s2, d);
        float4 o3 = shfl_xor4(s3, d);
        s3.x += o3.x + s2.x * o1.x + s1.x * o2.x;
        s3.y += o3.y + s2.y * o1.y + s1.y * o2.y;
        s3.z += o3.z + s2.z * o1.z + s1.z * o2.z;
        s3.w += o3.w + s2.w * o1.w + s1.w * o2.w;
        s2.x += o2.x + s1.x * o1.x;
        s2.y += o2.y + s1.y * o1.y;
        s2.z += o2.z + s1.z * o1.z;
        s2.w += o2.w + s1.w * o1.w;
        s1.x += o1.x; s1.y += o1.y; s1.z += o1.z; s1.w += o1.w;
    }

    // Sum e3 over components and over the 16 g-groups (lane bits 0..3).
    float r = (s3.x + s3.y) + (s3.z + s3.w);
    r += __shfl_xor(r, 1);
    r += __shfl_xor(r, 2);
    r += __shfl_xor(r, 4);
    r += __shfl_xor(r, 8);

    if (lane == 0) out[b] = r;
}

extern "C" void kernel_launch(void* const* d_in, const int* in_sizes, int n_in,
                              void* d_out, int out_size, void* d_ws, size_t ws_size,
                              hipStream_t stream) {
    const float* x = (const float*)d_in[0];
    float* out = (float*)d_out;
    const int total_threads = BATCH * 64;   // one wave per row
    dim3 grid(total_threads / 256);         // 2048 blocks
    anova3_kernel<<<grid, dim3(256), 0, stream>>>(x, out);
}

// Round 2
// 174.712 us; speedup vs baseline: 1.0626x; 1.0626x over previous
//
#include <hip/hip_runtime.h>

// ANOVA kernel order 3:  out[b] = sum_e e3(x[b, :, e])
// x: (8192, 64, 64) fp32, row-major, e innermost.
//
// R6: R4 structure (measured best, 184.72 us total / kernel ~24.75 us,
// 5.42 TB/s read) + NON-TEMPORAL loads.
//   - One wave per batch row; load i covers the row's float4 units
//     [i*64,(i+1)*64) -> each wave-load is 1 KB contiguous, 1 KB-aligned.
//   - Lane owns fields {4i + (lane>>4)} for embedding group g = lane&15;
//     ESP e_k(A∪B) merge over h = lane>>4 (shfl_xor 16,32), then e3 summed
//     over components and g (shfl_xor 1,2,4,8).
//   - R5 (occupancy push, 2x4 pipeline) was NEUTRAL -> not latency/TLP-bound.
//   - This round: __builtin_nontemporal_load on the x stream (134 MB, each
//     line read exactly once) to skip L1/L2 retention. Fills in the same
//     trace sustain 6.95 TB/s one-directional vs our 5.42 read; if TCC
//     allocate/evict is the gap, NT recovers part of it. If neutral ->
//     structural read roofline, stop.

constexpr int BATCH = 8192;

using f32x4 = __attribute__((ext_vector_type(4))) float;

__device__ inline f32x4 shfl_xor4(f32x4 v, int d) {
    f32x4 r;
    r.x = __shfl_xor(v.x, d);
    r.y = __shfl_xor(v.y, d);
    r.z = __shfl_xor(v.z, d);
    r.w = __shfl_xor(v.w, d);
    return r;
}

__global__ __launch_bounds__(256) void anova3_kernel(const float* __restrict__ x,
                                                     float* __restrict__ out) {
    const int tid  = blockIdx.x * 256 + threadIdx.x;
    const int lane = threadIdx.x & 63;
    const int b    = tid >> 6;        // one wave per batch row

    // Row = 1024 float4 units. Load i covers units [i*64, (i+1)*64): 1 KB contiguous.
    const f32x4* xp = reinterpret_cast<const f32x4*>(x)
                    + (size_t)b * 1024 + lane;

    f32x4 s1 = {0.f, 0.f, 0.f, 0.f};
    f32x4 s2 = s1, s3 = s1;

#pragma unroll
    for (int i = 0; i < 16; ++i) {
        f32x4 v = __builtin_nontemporal_load(xp + i * 64);
        // ESP DP; order matters: s3 uses old s2, s2 uses old s1
        s3.x = fmaf(s2.x, v.x, s3.x); s2.x = fmaf(s1.x, v.x, s2.x); s1.x += v.x;
        s3.y = fmaf(s2.y, v.y, s3.y); s2.y = fmaf(s1.y, v.y, s2.y); s1.y += v.y;
        s3.z = fmaf(s2.z, v.z, s3.z); s2.z = fmaf(s1.z, v.z, s2.z); s1.z += v.z;
        s3.w = fmaf(s2.w, v.w, s3.w); s2.w = fmaf(s1.w, v.w, s2.w); s1.w += v.w;
    }

    // Merge the 4 disjoint field subsets across h = lane>>4.
#pragma unroll
    for (int d = 16; d <= 32; d <<= 1) {
        f32x4 o1 = shfl_xor4(s1, d);
        f32x4 o2 = shfl_xor4(s2, d);
        f32x4 o3 = shfl_xor4(s3, d);
        s3.x += o3.x + s2.x * o1.x + s1.x * o2.x;
        s3.y += o3.y + s2.y * o1.y + s1.y * o2.y;
        s3.z += o3.z + s2.z * o1.z + s1.z * o2.z;
        s3.w += o3.w + s2.w * o1.w + s1.w * o2.w;
        s2.x += o2.x + s1.x * o1.x;
        s2.y += o2.y + s1.y * o1.y;
        s2.z += o2.z + s1.z * o1.z;
        s2.w += o2.w + s1.w * o1.w;
        s1.x += o1.x; s1.y += o1.y; s1.z += o1.z; s1.w += o1.w;
    }

    // Sum e3 over components and over the 16 g-groups (lane bits 0..3).
    float r = (s3.x + s3.y) + (s3.z + s3.w);
    r += __shfl_xor(r, 1);
    r += __shfl_xor(r, 2);
    r += __shfl_xor(r, 4);
    r += __shfl_xor(r, 8);

    if (lane == 0) out[b] = r;
}

extern "C" void kernel_launch(void* const* d_in, const int* in_sizes, int n_in,
                              void* d_out, int out_size, void* d_ws, size_t ws_size,
                              hipStream_t stream) {
    const float* x = (const float*)d_in[0];
    float* out = (float*)d_out;
    const int total_threads = BATCH * 64;   // one wave per row
    dim3 grid(total_threads / 256);         // 2048 blocks
    anova3_kernel<<<grid, dim3(256), 0, stream>>>(x, out);
}